// Round 5
// baseline (268.350 us; speedup 1.0000x reference)
//
#include <hip/hip_runtime.h>
#include <hip/hip_bf16.h>
#include <math.h>

// MoLE layer: out = gelu(x @ base_w^T + base_b) + top1_w * (gelu(x @ A[e]) @ B[e])
// probs = softmax(x @ gate_w^T + gate_b)
// T=8192 tokens, D=2048, E=8 experts, RANK=16.
//
// Pipeline (3 kernels):
//  k1 cvt_logits: token blocks (8 tokens each) convert x fp32->bf16 AND compute
//     fp32 logits with gate_w cached in REGISTERS. Logit reduction is an
//     expert-dim reduce-scatter (10 shuffles/token). Other blocks convert
//     base_w and do LDS-tiled transposes lora_B -> Bt, lora_A -> Ab.
//  k2 hsel: dense H = Xb @ Ab over ALL experts, 32x64 tile, BK=128 staging
//     (16 barrier rounds, 8 MFMA/round; half-major LDS keeps global_load_lds's
//     linear rule per 64-col half). Epilogue: one-hot A2 = (idx==e)*w*gelu(H).
//  k3 gemm: 128x128 bf16 MFMA GEMM, BK=32 with a 3-deep LDS ring (48 KB,
//     3 blocks/CU). Counted-vmcnt pipeline: stage tile T+2 while computing T,
//     one raw s_barrier per round, vmcnt(4) (T+1 stays in flight — never a
//     full drain in the main loop; this removes the ~30% barrier-drain stall
//     of the old 2-barrier BK=64 loop whose FETCH-halving L2 fix moved time
//     only 2%). Ring hazards proven by barrier-before-stage ordering; 4-slot
//     swizzle chunk = slot ^ (row&3) ^ ((row>>2)&1) gives 2-way-free ds_read.
//     Grid m-fastest: XCD = m%8 keeps 4MB A-slab L2-resident (FETCH 151->77MB).
//     Epilogue: +bias, GELU, LoRA as 4 extra K=32 MFMAs from A2/Bt, store fp32.

#define DIM   2048
#define RANK  16
#define NEXP  8
#define NTOK  8192
#define KLORA 128   // NEXP*RANK

typedef __hip_bfloat16 bf16;
typedef __attribute__((ext_vector_type(8))) short short8;  // 8 bf16 = 4 VGPRs
typedef __attribute__((ext_vector_type(4))) float float4v;

typedef const __attribute__((address_space(1))) void* gptr_t;
typedef __attribute__((address_space(3))) void*       sptr_t;

__device__ __forceinline__ void async_ld16(const bf16* g, bf16* l) {
    __builtin_amdgcn_global_load_lds((gptr_t)g, (sptr_t)l, 16, 0, 0);
}

// tanh-approx GELU: |err vs erf-gelu| <= ~3e-3, well under 0.1 threshold
__device__ __forceinline__ float gelu_fast(float x) {
    float t = 0.7978845608028654f * (x + 0.044715f * x * x * x);
    t = fminf(fmaxf(t, -10.0f), 10.0f);
    float e = __expf(2.0f * t);
    float th = (e - 1.0f) / (e + 1.0f);
    return 0.5f * x * (1.0f + th);
}

__device__ __forceinline__ short8 pack8(float4 v0, float4 v1) {
    union { bf16 h[8]; short8 v; } u;
    u.h[0] = __float2bfloat16(v0.x); u.h[1] = __float2bfloat16(v0.y);
    u.h[2] = __float2bfloat16(v0.z); u.h[3] = __float2bfloat16(v0.w);
    u.h[4] = __float2bfloat16(v1.x); u.h[5] = __float2bfloat16(v1.y);
    u.h[6] = __float2bfloat16(v1.z); u.h[7] = __float2bfloat16(v1.w);
    return u.v;
}

// --------------------------------------------------------- cvt+logits kernel
// blocks [0,1024): 8 tokens each, cvt + fp32 logits (gate_w in registers).
// [1024,3072): base_w cvt.  [3072,3328): Bt transpose.  [3328,3456): Ab transp.
__global__ __launch_bounds__(256) void cvt_logits_kernel(
    const float* __restrict__ x, const float* __restrict__ gate_w,
    const float* __restrict__ gate_b, const float* __restrict__ base_w,
    const float* __restrict__ lora_B, const float* __restrict__ lora_A,
    bf16* __restrict__ Xb, bf16* __restrict__ Wb,
    bf16* __restrict__ Bt, bf16* __restrict__ Ab,
    float* __restrict__ probs, int* __restrict__ idx_out, float* __restrict__ w_out)
{
    __shared__ float buf[2560];         // shared scratch for all branches
    const int b   = blockIdx.x;
    const int tid = threadIdx.x;

    if (b < 1024) {
        // ---- 8 tokens: convert + fp32 logits ----
        const int t0 = b * 8;
        float4 g0[NEXP], g1[NEXP];      // gate_w slice: 8 experts x 8 floats
        #pragma unroll
        for (int e = 0; e < NEXP; e++) {
            const float* wr = gate_w + (size_t)e * DIM + tid * 8;
            g0[e] = *(const float4*)wr;
            g1[e] = *(const float4*)(wr + 4);
        }
        const int wave = tid >> 6, lane = tid & 63;
        // expert owned by this lane after reduce-scatter: bitrev3(lane&7)
        const int eown = ((lane & 1) << 2) | (lane & 2) | ((lane & 4) >> 2);
        #pragma unroll
        for (int tt = 0; tt < 8; tt++) {
            const int t = t0 + tt;
            const float* xr = x + (size_t)t * DIM + tid * 8;
            float4 v0 = *(const float4*)xr;
            float4 v1 = *(const float4*)(xr + 4);
            *(short8*)(Xb + (size_t)t * DIM + tid * 8) = pack8(v0, v1);
            float a[NEXP];
            #pragma unroll
            for (int e = 0; e < NEXP; e++) {
                a[e] = v0.x * g0[e].x + v0.y * g0[e].y + v0.z * g0[e].z + v0.w * g0[e].w
                     + v1.x * g1[e].x + v1.y * g1[e].y + v1.z * g1[e].z + v1.w * g1[e].w;
            }
            // reduce-scatter over the expert dim within 8-lane groups:
            float b4[4];
            #pragma unroll
            for (int i = 0; i < 4; i++) {
                float send = (lane & 1) ? a[i]     : a[i + 4];
                float keep = (lane & 1) ? a[i + 4] : a[i];
                b4[i] = keep + __shfl_xor(send, 1);
            }
            float b2[2];
            #pragma unroll
            for (int i = 0; i < 2; i++) {
                float send = (lane & 2) ? b4[i]     : b4[i + 2];
                float keep = (lane & 2) ? b4[i + 2] : b4[i];
                b2[i] = keep + __shfl_xor(send, 2);
            }
            float send3 = (lane & 4) ? b2[0] : b2[1];
            float keep3 = (lane & 4) ? b2[1] : b2[0];
            float s = keep3 + __shfl_xor(send3, 4);
            s += __shfl_xor(s, 8);
            s += __shfl_xor(s, 16);
            s += __shfl_xor(s, 32);
            if (lane < NEXP) buf[tt * 32 + wave * NEXP + eown] = s;
        }
        __syncthreads();
        if (tid < 8) {                  // thread tid finalizes token t0+tid
            const int t = t0 + tid;
            float l[NEXP]; float mx = -1e30f;
            #pragma unroll
            for (int e = 0; e < NEXP; e++) {
                l[e] = buf[tid * 32 + e] + buf[tid * 32 + 8 + e]
                     + buf[tid * 32 + 16 + e] + buf[tid * 32 + 24 + e] + gate_b[e];
                mx = fmaxf(mx, l[e]);
            }
            float sum = 0.f;
            #pragma unroll
            for (int e = 0; e < NEXP; e++) { l[e] = __expf(l[e] - mx); sum += l[e]; }
            float inv = 1.0f / sum;
            int es = 0; float best = l[0];
            #pragma unroll
            for (int e = 1; e < NEXP; e++) if (l[e] > best) { best = l[e]; es = e; }
            #pragma unroll
            for (int e = 0; e < NEXP; e++) probs[(size_t)t * NEXP + e] = l[e] * inv;
            idx_out[t] = es;
            w_out[t]   = best * inv;
        }
    } else if (b < 1024 + 2048) {
        // ---- base_w convert: 8 floats/thread ----
        size_t v = ((size_t)(b - 1024) * 256 + tid) * 8;
        float4 v0 = *(const float4*)(base_w + v);
        float4 v1 = *(const float4*)(base_w + v + 4);
        *(short8*)(Wb + v) = pack8(v0, v1);
    } else if (b < 1024 + 2048 + 256) {
        // ---- Bt transpose: lora_B [128][2048] -> Bt [2048][128], 32x32 tile
        int bb = b - 1024 - 2048;
        int kk0 = (bb >> 6) * 32, j0 = (bb & 63) * 32;
        {   // read coalesced along j
            int r = tid >> 3, c4 = (tid & 7) * 4;
            float4 val = *(const float4*)(lora_B + (size_t)(kk0 + r) * DIM + j0 + c4);
            *(float4*)(buf + r * 36 + c4) = val;
        }
        __syncthreads();
        {   // write coalesced along kk
            int j = tid >> 3, k4 = (tid & 7) * 4;
            bf16* dst = Bt + (size_t)(j0 + j) * KLORA + kk0 + k4;
            #pragma unroll
            for (int i = 0; i < 4; i++) dst[i] = __float2bfloat16(buf[(k4 + i) * 36 + j]);
        }
    } else {
        // ---- Ab transpose: lora_A [8][2048][16] -> Ab [128][2048]
        int bb = b - 1024 - 2048 - 256;
        int e = bb >> 4, k0 = (bb & 15) * 128;
        const float* src = lora_A + (size_t)e * DIM * RANK;
        {
            int k = tid >> 2, r4 = (tid & 3) * 4;
            float4 va = *(const float4*)(src + (size_t)(k0 + k) * RANK + r4);
            float4 vb = *(const float4*)(src + (size_t)(k0 + k + 64) * RANK + r4);
            *(float4*)(buf + k * 20 + r4)        = va;
            *(float4*)(buf + (k + 64) * 20 + r4) = vb;
        }
        __syncthreads();
        {
            int r = tid >> 4, kx = (tid & 15) * 8;
            bf16* dst = Ab + (size_t)(e * 16 + r) * DIM + k0 + kx;
            #pragma unroll
            for (int i = 0; i < 8; i++) dst[i] = __float2bfloat16(buf[(kx + i) * 20 + r]);
        }
    }
}

// ---------------------------------------------------------------- hsel kernel
// H = Xb @ Ab (all experts, K=2048), 32x64 tile, BK=128, grid (256,2).
// LDS is half-major: As[2][32][64], Bs[2][64][64]; proven 8-slot XOR within
// each 64-col half. Epilogue: A2[t][jcol] = (idx[t]==jcol>>4) * w[t] * gelu(H).
__global__ __launch_bounds__(256) void hsel_kernel(
    const bf16* __restrict__ Xb, const bf16* __restrict__ Ab,
    const int* __restrict__ idx, const float* __restrict__ wsel,
    bf16* __restrict__ A2)
{
    __shared__ bf16 As[2 * 32 * 64];    // 8 KB  [half][row][64]
    __shared__ bf16 Bs[2 * 64 * 64];    // 16 KB [half][row][64]
    const int tid  = threadIdx.x;
    const int wave = tid >> 6, lane = tid & 63;
    const int m0 = blockIdx.x * 32;
    const int n0 = blockIdx.y * 64;
    const int col = lane & 15, quad = lane >> 4;

    // staging: per half, A = 1 round (rows 0..31), B = 2 rounds (0..31, 32..63)
    const int kc = ((tid & 7) ^ ((tid >> 3) & 7)) * 8;   // within-half chunk
    const int sr = tid >> 3;                       // 0..31
    const bf16* gA  = Xb + (size_t)(m0 + sr) * DIM + kc;
    const bf16* gB0 = Ab + (size_t)(n0 + sr) * DIM + kc;
    const bf16* gB1 = gB0 + (size_t)32 * DIM;      // rows 32..63 (row&7 kept)
    bf16* lA = As + wave * 512;                    // wave-uniform LDS base
    bf16* lB = Bs + wave * 512;

    int slot[4];
    #pragma unroll
    for (int ks = 0; ks < 4; ks++)
        slot[ks] = ((((ks & 1) << 2) | quad) ^ (col & 7)) * 8;
    const bf16* pa = As + col * 64;                // + h*2048 + i*1024
    const bf16* pb = Bs + (wave * 16 + col) * 64;  // + h*4096

    float4v acc[2] = {};
    for (int k0 = 0; k0 < DIM; k0 += 128) {
        __syncthreads();
        async_ld16(gA  + k0,      lA);              // A half0
        async_ld16(gA  + k0 + 64, lA + 2048);       // A half1
        async_ld16(gB0 + k0,      lB);              // B half0 rows 0-31
        async_ld16(gB1 + k0,      lB + 2048);       // B half0 rows 32-63
        async_ld16(gB0 + k0 + 64, lB + 4096);       // B half1 rows 0-31
        async_ld16(gB1 + k0 + 64, lB + 6144);       // B half1 rows 32-63
        __syncthreads();
        #pragma unroll
        for (int ks = 0; ks < 4; ks++) {
            const int h = ks >> 1;
            short8 a0 = *(const short8*)(pa + h * 2048 + slot[ks]);
            short8 a1 = *(const short8*)(pa + h * 2048 + 1024 + slot[ks]);
            short8 b0 = *(const short8*)(pb + h * 4096 + slot[ks]);
            acc[0] = __builtin_amdgcn_mfma_f32_16x16x32_bf16(a0, b0, acc[0], 0, 0, 0);
            acc[1] = __builtin_amdgcn_mfma_f32_16x16x32_bf16(a1, b0, acc[1], 0, 0, 0);
        }
    }

    const int jcol = n0 + wave * 16 + col;
    const int ej   = jcol >> 4;
    #pragma unroll
    for (int i = 0; i < 2; i++) {
        int rbase = m0 + i * 16 + quad * 4;
        #pragma unroll
        for (int r = 0; r < 4; r++) {
            int t = rbase + r;
            float v = (idx[t] == ej) ? gelu_fast(acc[i][r]) * wsel[t] : 0.0f;
            A2[(size_t)t * KLORA + jcol] = __float2bfloat16(v);
        }
    }
}

// --------------------------------------------------------------- GEMM kernel
// BK=32, 3-deep LDS ring, counted vmcnt(4), one s_barrier per round.
// Round T: {vmcnt(4) [tile T resident, T+1 in flight] -> s_barrier ->
//  stage T+2 into buf (T+2)%3 [== (T-1)%3, readers retired before barrier] ->
//  ds_read tile T frags -> lgkmcnt(0) -> 16 MFMA}.
// Fast-wave safety: the next stage into buf T%3 sits behind the NEXT barrier,
// which a slow reader of buf T%3 has not yet reached.
__global__ __launch_bounds__(256, 3) void gemm_kernel(
    const bf16* __restrict__ Xb, const bf16* __restrict__ Wb,
    const float* __restrict__ base_b,
    const bf16* __restrict__ A2, const bf16* __restrict__ Bt,
    float* __restrict__ out)
{
    __shared__ bf16 As[3 * 128 * 32];   // 24 KB ring
    __shared__ bf16 Bs[3 * 128 * 32];   // 24 KB ring
    const int tid  = threadIdx.x;
    const int wave = tid >> 6, lane = tid & 63;
    const int wm = wave >> 1, wn = wave & 1;
    const int m0 = blockIdx.x * 128;    // m fastest: XCD = m%8 (A-slab locality)
    const int n0 = blockIdx.y * 128;
    const int col = lane & 15, quad = lane >> 4;

    // staging: tile = 128 rows x 32 elems (64 B rows, 4 slots of 16 B).
    // 2 rounds of 256 threads per matrix: row = r*64 + (tid>>2), slot = tid&3,
    // global chunk = slot ^ f(row), f(row) = (row&3) ^ ((row>>2)&1).
    // LDS byte = row*64 + slot*16 = r*4096B + tid*16B  -> linear per lane.
    const int c4 = ((tid & 3) ^ ((tid >> 2) & 3) ^ ((tid >> 4) & 1)) * 8;
    const int srow = tid >> 2;          // 0..63
    const bf16* gA0 = Xb + (size_t)(m0 + srow) * DIM + c4;
    const bf16* gB0 = Wb + (size_t)(n0 + srow) * DIM + c4;
    const bf16* gA1 = gA0 + (size_t)64 * DIM;
    const bf16* gB1 = gB0 + (size_t)64 * DIM;
    bf16* lA = As + wave * 512;         // wave-uniform; +2048 round1, +4096/buf
    bf16* lB = Bs + wave * 512;

    // frag read: row = wm*64 + i*16 + col; chunk quad ->
    // slot = quad ^ (col&3) ^ ((col>>2)&1)   (2 lanes per 16B-position mod 128
    // -> 2-way, free). 16-row / 64-row offsets preserve row&3 and (row>>2)&1.
    const int slq = ((quad ^ (col & 3) ^ ((col >> 2) & 1))) * 8;
    const bf16* paA = As + (wm * 64 + col) * 32 + slq;
    const bf16* pbB = Bs + (wn * 64 + col) * 32 + slq;

    float4v acc[4][4] = {};

    // prologue: stage tiles 0,1 into bufs 0,1 (8 loads/thread)
    #pragma unroll
    for (int t = 0; t < 2; t++) {
        async_ld16(gA0 + t * 32, lA + t * 4096);
        async_ld16(gA1 + t * 32, lA + t * 4096 + 2048);
        async_ld16(gB0 + t * 32, lB + t * 4096);
        async_ld16(gB1 + t * 32, lB + t * 4096 + 2048);
    }

    int bufc = 0, bufs = 2;             // compute buffer, stage buffer
    for (int T = 0; T < 64; T++) {
        // tile T resident; allow tile T+1's 4 loads to stay in flight
        if (T < 63) asm volatile("s_waitcnt vmcnt(4)" ::: "memory");
        else        asm volatile("s_waitcnt vmcnt(0)" ::: "memory");
        __builtin_amdgcn_sched_barrier(0);
        __builtin_amdgcn_s_barrier();
        __builtin_amdgcn_sched_barrier(0);
        if (T < 62) {                   // stage tile T+2 into buf (T+2)%3
            const int ko = (T + 2) * 32;
            bf16* la = lA + bufs * 4096;
            bf16* lb = lB + bufs * 4096;
            async_ld16(gA0 + ko, la);
            async_ld16(gA1 + ko, la + 2048);
            async_ld16(gB0 + ko, lb);
            async_ld16(gB1 + ko, lb + 2048);
        }
        const bf16* pa = paA + bufc * 4096;
        const bf16* pb = pbB + bufc * 4096;
        short8 a[4], b[4];
        #pragma unroll
        for (int i = 0; i < 4; i++) a[i] = *(const short8*)(pa + i * 512);
        #pragma unroll
        for (int j = 0; j < 4; j++) b[j] = *(const short8*)(pb + j * 512);
        asm volatile("s_waitcnt lgkmcnt(0)" ::: "memory");
        __builtin_amdgcn_sched_barrier(0);
        #pragma unroll
        for (int i = 0; i < 4; i++)
            #pragma unroll
            for (int j = 0; j < 4; j++)
                acc[i][j] = __builtin_amdgcn_mfma_f32_16x16x32_bf16(
                    a[i], b[j], acc[i][j], 0, 0, 0);
        bufc = (bufc == 2) ? 0 : bufc + 1;
        bufs = (bufs == 2) ? 0 : bufs + 1;
    }

    // epilogue 1: bias + GELU (C/D: row = quad*4+reg, col = lane&15)
    float bias[4];
    #pragma unroll
    for (int j = 0; j < 4; j++) bias[j] = base_b[n0 + wn * 64 + j * 16 + col];
    #pragma unroll
    for (int i = 0; i < 4; i++)
        #pragma unroll
        for (int j = 0; j < 4; j++)
            #pragma unroll
            for (int r = 0; r < 4; r++)
                acc[i][j][r] = gelu_fast(acc[i][j][r] + bias[j]);

    // epilogue 2: LoRA as K=128 MFMA extension (4 steps of K=32)
    const bf16* pea = A2 + (size_t)(m0 + wm * 64 + col) * KLORA + quad * 8;
    const bf16* peb = Bt + (size_t)(n0 + wn * 64 + col) * KLORA + quad * 8;
    #pragma unroll
    for (int ks = 0; ks < 4; ks++) {
        short8 ea[4], eb[4];
        #pragma unroll
        for (int i = 0; i < 4; i++)
            ea[i] = *(const short8*)(pea + i * 16 * KLORA + ks * 32);
        #pragma unroll
        for (int j = 0; j < 4; j++)
            eb[j] = *(const short8*)(peb + j * 16 * KLORA + ks * 32);
        #pragma unroll
        for (int i = 0; i < 4; i++)
            #pragma unroll
            for (int j = 0; j < 4; j++)
                acc[i][j] = __builtin_amdgcn_mfma_f32_16x16x32_bf16(
                    ea[i], eb[j], acc[i][j], 0, 0, 0);
    }

    // store fp32
    #pragma unroll
    for (int i = 0; i < 4; i++) {
        #pragma unroll
        for (int j = 0; j < 4; j++) {
            int tt = m0 + wm * 64 + i * 16 + quad * 4;
            int jj = n0 + wn * 64 + j * 16 + col;
            float* po = out + (size_t)tt * DIM + jj;
            #pragma unroll
            for (int r = 0; r < 4; r++) po[(size_t)r * DIM] = acc[i][j][r];
        }
    }
}

// ------------------------------------------------------------------- launch
extern "C" void kernel_launch(void* const* d_in, const int* in_sizes, int n_in,
                              void* d_out, int out_size, void* d_ws, size_t ws_size,
                              hipStream_t stream)
{
    (void)in_sizes; (void)n_in; (void)out_size; (void)ws_size;
    const float* x      = (const float*)d_in[0];
    const float* gate_w = (const float*)d_in[1];
    const float* gate_b = (const float*)d_in[2];
    const float* base_w = (const float*)d_in[3];
    const float* base_b = (const float*)d_in[4];
    const float* lora_A = (const float*)d_in[5];
    const float* lora_B = (const float*)d_in[6];

    float* out   = (float*)d_out;                    // [8192, 2048]
    float* probs = out + (size_t)NTOK * DIM;         // [8192, 8]

    // workspace layout (~45.2 MB)
    char* ws = (char*)d_ws;
    bf16*  Xb   = (bf16*)ws;                          // 33,554,432 B
    bf16*  Wb   = (bf16*)(ws + 33554432);             //  8,388,608 B
    bf16*  A2   = (bf16*)(ws + 41943040);             //  2,097,152 B
    bf16*  Bt   = (bf16*)(ws + 44040192);             //    524,288 B
    bf16*  Ab   = (bf16*)(ws + 44564480);             //    524,288 B
    int*   idx  = (int*) (ws + 45088768);             //     32,768 B
    float* wsel = (float*)(ws + 45121536);            //     32,768 B

    cvt_logits_kernel<<<1024 + 2048 + 256 + 128, 256, 0, stream>>>(
        x, gate_w, gate_b, base_w, lora_B, lora_A,
        Xb, Wb, Bt, Ab, probs, idx, wsel);
    hsel_kernel<<<dim3(256, 2), 256, 0, stream>>>(Xb, Ab, idx, wsel, A2);
    gemm_kernel<<<dim3(64, 16), 256, 0, stream>>>(Xb, Wb, base_b, A2, Bt, out);
}

// Round 6
// 243.736 us; speedup vs baseline: 1.1010x; 1.1010x over previous
//
#include <hip/hip_runtime.h>
#include <hip/hip_bf16.h>
#include <math.h>

// MoLE layer: out = gelu(x @ base_w^T + base_b) + top1_w * (gelu(x @ A[e]) @ B[e])
// probs = softmax(x @ gate_w^T + gate_b)
// T=8192 tokens, D=2048, E=8 experts, RANK=16.
//
// Pipeline (3 kernels):
//  k1 cvt_logits: token blocks (8 tokens each) convert x fp32->bf16 AND compute
//     fp32 logits with gate_w cached in REGISTERS. Logit reduction is an
//     expert-dim reduce-scatter (10 shuffles/token). Other blocks convert
//     base_w and do LDS-tiled transposes lora_B -> Bt, lora_A -> Ab.
//  k2 hsel: dense H = Xb @ Ab over ALL experts, 32x64 tile, BK=256 staging
//     (8 barrier rounds, 16 MFMA/round; quarter-major LDS [4][rows][64] keeps
//     global_load_lds's linear rule per 64-col quarter), proven 8-slot XOR
//     swizzle within each quarter. Epilogue: one-hot A2 = (idx==e)*w*gelu(H).
//  k3 gemm: 128x128 bf16 MFMA GEMM, BK=64 staging (2-barrier structure —
//     measured local optimum; R1 8-phase port and R5 3-ring both regressed,
//     R5 additionally showed DMA-write/ds_read overlap creates LDS bank
//     conflicts). 8-slot XOR-swizzled LDS (conflict-free ds_read_b128).
//     Grid m-fastest: XCD = m%8 keeps 4MB A-slab L2-resident (FETCH 151->77MB,
//     verified R4). Epilogue: +bias, GELU, LoRA as 4 extra K=32 MFMAs from
//     A2/Bt, store fp32.

#define DIM   2048
#define RANK  16
#define NEXP  8
#define NTOK  8192
#define KLORA 128   // NEXP*RANK

typedef __hip_bfloat16 bf16;
typedef __attribute__((ext_vector_type(8))) short short8;  // 8 bf16 = 4 VGPRs
typedef __attribute__((ext_vector_type(4))) float float4v;

typedef const __attribute__((address_space(1))) void* gptr_t;
typedef __attribute__((address_space(3))) void*       sptr_t;

__device__ __forceinline__ void async_ld16(const bf16* g, bf16* l) {
    __builtin_amdgcn_global_load_lds((gptr_t)g, (sptr_t)l, 16, 0, 0);
}

// tanh-approx GELU: |err vs erf-gelu| <= ~3e-3, well under 0.1 threshold
__device__ __forceinline__ float gelu_fast(float x) {
    float t = 0.7978845608028654f * (x + 0.044715f * x * x * x);
    t = fminf(fmaxf(t, -10.0f), 10.0f);
    float e = __expf(2.0f * t);
    float th = (e - 1.0f) / (e + 1.0f);
    return 0.5f * x * (1.0f + th);
}

__device__ __forceinline__ short8 pack8(float4 v0, float4 v1) {
    union { bf16 h[8]; short8 v; } u;
    u.h[0] = __float2bfloat16(v0.x); u.h[1] = __float2bfloat16(v0.y);
    u.h[2] = __float2bfloat16(v0.z); u.h[3] = __float2bfloat16(v0.w);
    u.h[4] = __float2bfloat16(v1.x); u.h[5] = __float2bfloat16(v1.y);
    u.h[6] = __float2bfloat16(v1.z); u.h[7] = __float2bfloat16(v1.w);
    return u.v;
}

// --------------------------------------------------------- cvt+logits kernel
// blocks [0,1024): 8 tokens each, cvt + fp32 logits (gate_w in registers).
// [1024,3072): base_w cvt.  [3072,3328): Bt transpose.  [3328,3456): Ab transp.
__global__ __launch_bounds__(256) void cvt_logits_kernel(
    const float* __restrict__ x, const float* __restrict__ gate_w,
    const float* __restrict__ gate_b, const float* __restrict__ base_w,
    const float* __restrict__ lora_B, const float* __restrict__ lora_A,
    bf16* __restrict__ Xb, bf16* __restrict__ Wb,
    bf16* __restrict__ Bt, bf16* __restrict__ Ab,
    float* __restrict__ probs, int* __restrict__ idx_out, float* __restrict__ w_out)
{
    __shared__ float buf[2560];         // shared scratch for all branches
    const int b   = blockIdx.x;
    const int tid = threadIdx.x;

    if (b < 1024) {
        // ---- 8 tokens: convert + fp32 logits ----
        const int t0 = b * 8;
        float4 g0[NEXP], g1[NEXP];      // gate_w slice: 8 experts x 8 floats
        #pragma unroll
        for (int e = 0; e < NEXP; e++) {
            const float* wr = gate_w + (size_t)e * DIM + tid * 8;
            g0[e] = *(const float4*)wr;
            g1[e] = *(const float4*)(wr + 4);
        }
        const int wave = tid >> 6, lane = tid & 63;
        // expert owned by this lane after reduce-scatter: bitrev3(lane&7)
        const int eown = ((lane & 1) << 2) | (lane & 2) | ((lane & 4) >> 2);
        #pragma unroll
        for (int tt = 0; tt < 8; tt++) {
            const int t = t0 + tt;
            const float* xr = x + (size_t)t * DIM + tid * 8;
            float4 v0 = *(const float4*)xr;
            float4 v1 = *(const float4*)(xr + 4);
            *(short8*)(Xb + (size_t)t * DIM + tid * 8) = pack8(v0, v1);
            float a[NEXP];
            #pragma unroll
            for (int e = 0; e < NEXP; e++) {
                a[e] = v0.x * g0[e].x + v0.y * g0[e].y + v0.z * g0[e].z + v0.w * g0[e].w
                     + v1.x * g1[e].x + v1.y * g1[e].y + v1.z * g1[e].z + v1.w * g1[e].w;
            }
            // reduce-scatter over the expert dim within 8-lane groups:
            float b4[4];
            #pragma unroll
            for (int i = 0; i < 4; i++) {
                float send = (lane & 1) ? a[i]     : a[i + 4];
                float keep = (lane & 1) ? a[i + 4] : a[i];
                b4[i] = keep + __shfl_xor(send, 1);
            }
            float b2[2];
            #pragma unroll
            for (int i = 0; i < 2; i++) {
                float send = (lane & 2) ? b4[i]     : b4[i + 2];
                float keep = (lane & 2) ? b4[i + 2] : b4[i];
                b2[i] = keep + __shfl_xor(send, 2);
            }
            float send3 = (lane & 4) ? b2[0] : b2[1];
            float keep3 = (lane & 4) ? b2[1] : b2[0];
            float s = keep3 + __shfl_xor(send3, 4);
            s += __shfl_xor(s, 8);
            s += __shfl_xor(s, 16);
            s += __shfl_xor(s, 32);
            if (lane < NEXP) buf[tt * 32 + wave * NEXP + eown] = s;
        }
        __syncthreads();
        if (tid < 8) {                  // thread tid finalizes token t0+tid
            const int t = t0 + tid;
            float l[NEXP]; float mx = -1e30f;
            #pragma unroll
            for (int e = 0; e < NEXP; e++) {
                l[e] = buf[tid * 32 + e] + buf[tid * 32 + 8 + e]
                     + buf[tid * 32 + 16 + e] + buf[tid * 32 + 24 + e] + gate_b[e];
                mx = fmaxf(mx, l[e]);
            }
            float sum = 0.f;
            #pragma unroll
            for (int e = 0; e < NEXP; e++) { l[e] = __expf(l[e] - mx); sum += l[e]; }
            float inv = 1.0f / sum;
            int es = 0; float best = l[0];
            #pragma unroll
            for (int e = 1; e < NEXP; e++) if (l[e] > best) { best = l[e]; es = e; }
            #pragma unroll
            for (int e = 0; e < NEXP; e++) probs[(size_t)t * NEXP + e] = l[e] * inv;
            idx_out[t] = es;
            w_out[t]   = best * inv;
        }
    } else if (b < 1024 + 2048) {
        // ---- base_w convert: 8 floats/thread ----
        size_t v = ((size_t)(b - 1024) * 256 + tid) * 8;
        float4 v0 = *(const float4*)(base_w + v);
        float4 v1 = *(const float4*)(base_w + v + 4);
        *(short8*)(Wb + v) = pack8(v0, v1);
    } else if (b < 1024 + 2048 + 256) {
        // ---- Bt transpose: lora_B [128][2048] -> Bt [2048][128], 32x32 tile
        int bb = b - 1024 - 2048;
        int kk0 = (bb >> 6) * 32, j0 = (bb & 63) * 32;
        {   // read coalesced along j
            int r = tid >> 3, c4 = (tid & 7) * 4;
            float4 val = *(const float4*)(lora_B + (size_t)(kk0 + r) * DIM + j0 + c4);
            *(float4*)(buf + r * 36 + c4) = val;
        }
        __syncthreads();
        {   // write coalesced along kk
            int j = tid >> 3, k4 = (tid & 7) * 4;
            bf16* dst = Bt + (size_t)(j0 + j) * KLORA + kk0 + k4;
            #pragma unroll
            for (int i = 0; i < 4; i++) dst[i] = __float2bfloat16(buf[(k4 + i) * 36 + j]);
        }
    } else {
        // ---- Ab transpose: lora_A [8][2048][16] -> Ab [128][2048]
        int bb = b - 1024 - 2048 - 256;
        int e = bb >> 4, k0 = (bb & 15) * 128;
        const float* src = lora_A + (size_t)e * DIM * RANK;
        {
            int k = tid >> 2, r4 = (tid & 3) * 4;
            float4 va = *(const float4*)(src + (size_t)(k0 + k) * RANK + r4);
            float4 vb = *(const float4*)(src + (size_t)(k0 + k + 64) * RANK + r4);
            *(float4*)(buf + k * 20 + r4)        = va;
            *(float4*)(buf + (k + 64) * 20 + r4) = vb;
        }
        __syncthreads();
        {
            int r = tid >> 4, kx = (tid & 15) * 8;
            bf16* dst = Ab + (size_t)(e * 16 + r) * DIM + k0 + kx;
            #pragma unroll
            for (int i = 0; i < 8; i++) dst[i] = __float2bfloat16(buf[(kx + i) * 20 + r]);
        }
    }
}

// ---------------------------------------------------------------- hsel kernel
// H = Xb @ Ab (all experts, K=2048), 32x64 tile, BK=256, grid (256,2).
// LDS is quarter-major: As[4][32][64], Bs[4][64][64] — within each 64-col
// quarter, row stride is 64 elems so global_load_lds's linear (base+lane*16B)
// rule holds, and the proven 8-slot XOR applies: LDS slot s of row r holds
// global chunk s^(r&7) within that quarter.
// Frag reads, kstep ks (0..7): quarter h=ks>>1, parity p=ks&1; local chunk =
// p*4+quad -> slot = ((p<<2)|quad)^(col&7) (rows satisfy row&7==col&7).
// 8 barrier rounds (was 16 at BK=128), 16 MFMA/round.
// Epilogue: A2[t][jcol] = (idx[t]==jcol>>4) * w[t] * gelu(H).
__global__ __launch_bounds__(256) void hsel_kernel(
    const bf16* __restrict__ Xb, const bf16* __restrict__ Ab,
    const int* __restrict__ idx, const float* __restrict__ wsel,
    bf16* __restrict__ A2)
{
    __shared__ bf16 As[4 * 32 * 64];    // 16 KB [quarter][row][64]
    __shared__ bf16 Bs[4 * 64 * 64];    // 32 KB [quarter][row][64]
    const int tid  = threadIdx.x;
    const int wave = tid >> 6, lane = tid & 63;
    const int m0 = blockIdx.x * 32;
    const int n0 = blockIdx.y * 64;
    const int col = lane & 15, quad = lane >> 4;

    // staging: per quarter, A = 1 round (rows 0..31), B = 2 rounds (0..31,32..63)
    const int kc = ((tid & 7) ^ ((tid >> 3) & 7)) * 8;   // within-quarter chunk
    const int sr = tid >> 3;                       // 0..31
    const bf16* gA  = Xb + (size_t)(m0 + sr) * DIM + kc;
    const bf16* gB0 = Ab + (size_t)(n0 + sr) * DIM + kc;
    const bf16* gB1 = gB0 + (size_t)32 * DIM;      // rows 32..63 (row&7 kept)
    bf16* lA = As + wave * 512;                    // wave-uniform LDS base
    bf16* lB = Bs + wave * 512;

    int slot[2];
    #pragma unroll
    for (int p = 0; p < 2; p++)
        slot[p] = (((p << 2) | quad) ^ (col & 7)) * 8;
    const bf16* pa = As + col * 64;                // + h*2048 + i*1024
    const bf16* pb = Bs + (wave * 16 + col) * 64;  // + h*4096

    float4v acc[2] = {};
    for (int k0 = 0; k0 < DIM; k0 += 256) {
        __syncthreads();
        #pragma unroll
        for (int h = 0; h < 4; h++) {
            async_ld16(gA  + k0 + h * 64, lA + h * 2048);
            async_ld16(gB0 + k0 + h * 64, lB + h * 4096);
            async_ld16(gB1 + k0 + h * 64, lB + h * 4096 + 2048);
        }
        __syncthreads();
        #pragma unroll
        for (int ks = 0; ks < 8; ks++) {
            const int h = ks >> 1, p = ks & 1;
            short8 a0 = *(const short8*)(pa + h * 2048 + slot[p]);
            short8 a1 = *(const short8*)(pa + h * 2048 + 1024 + slot[p]);
            short8 b0 = *(const short8*)(pb + h * 4096 + slot[p]);
            acc[0] = __builtin_amdgcn_mfma_f32_16x16x32_bf16(a0, b0, acc[0], 0, 0, 0);
            acc[1] = __builtin_amdgcn_mfma_f32_16x16x32_bf16(a1, b0, acc[1], 0, 0, 0);
        }
    }

    const int jcol = n0 + wave * 16 + col;
    const int ej   = jcol >> 4;
    #pragma unroll
    for (int i = 0; i < 2; i++) {
        int rbase = m0 + i * 16 + quad * 4;
        #pragma unroll
        for (int r = 0; r < 4; r++) {
            int t = rbase + r;
            float v = (idx[t] == ej) ? gelu_fast(acc[i][r]) * wsel[t] : 0.0f;
            A2[(size_t)t * KLORA + jcol] = __float2bfloat16(v);
        }
    }
}

// --------------------------------------------------------------- GEMM kernel
// BK=64 staging (32 barrier rounds), two K=32 MFMA passes per staged buffer.
// Grid is m-fastest (dim3(64,16)): XCD = bid%8 = m%8 -> per-XCD 4MB A-slab
// stays L2-resident, Wb streamed once per XCD.
__global__ __launch_bounds__(256, 3) void gemm_kernel(
    const bf16* __restrict__ Xb, const bf16* __restrict__ Wb,
    const float* __restrict__ base_b,
    const bf16* __restrict__ A2, const bf16* __restrict__ Bt,
    float* __restrict__ out)
{
    __shared__ bf16 As[128 * 64];   // 16 KB
    __shared__ bf16 Bs[128 * 64];   // 16 KB
    const int tid  = threadIdx.x;
    const int wave = tid >> 6, lane = tid & 63;
    const int wm = wave >> 1, wn = wave & 1;
    const int m0 = blockIdx.x * 128;    // m fastest: XCD = m%8 (A-slab locality)
    const int n0 = blockIdx.y * 128;
    const int col = lane & 15, quad = lane >> 4;

    // staging: 1024 16B chunks per tile, 4 rounds of 256 threads.
    // LDS slot (tid&7) of row (tid>>3)+32u holds global k-chunk (tid&7)^((tid>>3)&7)
    const int kc = (((tid & 7) ^ ((tid >> 3) & 7))) * 8;
    const int r0 = tid >> 3;            // 0..31
    const bf16* gA0 = Xb + (size_t)(m0 + r0) * DIM + kc;
    const bf16* gB0 = Wb + (size_t)(n0 + r0) * DIM + kc;
    const bf16* gA1 = gA0 + (size_t)32 * DIM;
    const bf16* gB1 = gB0 + (size_t)32 * DIM;
    const bf16* gA2 = gA0 + (size_t)64 * DIM;
    const bf16* gB2 = gB0 + (size_t)64 * DIM;
    const bf16* gA3 = gA0 + (size_t)96 * DIM;
    const bf16* gB3 = gB0 + (size_t)96 * DIM;
    bf16* lA = As + wave * 512;         // +2048 per round
    bf16* lB = Bs + wave * 512;

    // frag read: row = wm*64+i*16+col (row&7 == col&7); slot = (4s+quad)^(col&7)
    const int sl0 = (quad        ^ (col & 7)) * 8;
    const int sl1 = ((quad | 4)  ^ (col & 7)) * 8;
    const bf16* paA = As + (wm * 64 + col) * 64;
    const bf16* pbB = Bs + (wn * 64 + col) * 64;

    float4v acc[4][4] = {};

    for (int k0 = 0; k0 < DIM; k0 += 64) {
        __syncthreads();
        async_ld16(gA0 + k0, lA);
        async_ld16(gA1 + k0, lA + 2048);
        async_ld16(gA2 + k0, lA + 4096);
        async_ld16(gA3 + k0, lA + 6144);
        async_ld16(gB0 + k0, lB);
        async_ld16(gB1 + k0, lB + 2048);
        async_ld16(gB2 + k0, lB + 4096);
        async_ld16(gB3 + k0, lB + 6144);
        __syncthreads();
        {   // K-step 0 (k0 .. k0+32)
            short8 a[4], b[4];
            #pragma unroll
            for (int i = 0; i < 4; i++) a[i] = *(const short8*)(paA + i * 1024 + sl0);
            #pragma unroll
            for (int j = 0; j < 4; j++) b[j] = *(const short8*)(pbB + j * 1024 + sl0);
            #pragma unroll
            for (int i = 0; i < 4; i++)
                #pragma unroll
                for (int j = 0; j < 4; j++)
                    acc[i][j] = __builtin_amdgcn_mfma_f32_16x16x32_bf16(
                        a[i], b[j], acc[i][j], 0, 0, 0);
        }
        {   // K-step 1 (k0+32 .. k0+64)
            short8 a[4], b[4];
            #pragma unroll
            for (int i = 0; i < 4; i++) a[i] = *(const short8*)(paA + i * 1024 + sl1);
            #pragma unroll
            for (int j = 0; j < 4; j++) b[j] = *(const short8*)(pbB + j * 1024 + sl1);
            #pragma unroll
            for (int i = 0; i < 4; i++)
                #pragma unroll
                for (int j = 0; j < 4; j++)
                    acc[i][j] = __builtin_amdgcn_mfma_f32_16x16x32_bf16(
                        a[i], b[j], acc[i][j], 0, 0, 0);
        }
    }

    // epilogue 1: bias + GELU (C/D: row = quad*4+reg, col = lane&15)
    float bias[4];
    #pragma unroll
    for (int j = 0; j < 4; j++) bias[j] = base_b[n0 + wn * 64 + j * 16 + col];
    #pragma unroll
    for (int i = 0; i < 4; i++)
        #pragma unroll
        for (int j = 0; j < 4; j++)
            #pragma unroll
            for (int r = 0; r < 4; r++)
                acc[i][j][r] = gelu_fast(acc[i][j][r] + bias[j]);

    // epilogue 2: LoRA as K=128 MFMA extension (4 steps of K=32)
    const bf16* pea = A2 + (size_t)(m0 + wm * 64 + col) * KLORA + quad * 8;
    const bf16* peb = Bt + (size_t)(n0 + wn * 64 + col) * KLORA + quad * 8;
    #pragma unroll
    for (int ks = 0; ks < 4; ks++) {
        short8 ea[4], eb[4];
        #pragma unroll
        for (int i = 0; i < 4; i++)
            ea[i] = *(const short8*)(pea + i * 16 * KLORA + ks * 32);
        #pragma unroll
        for (int j = 0; j < 4; j++)
            eb[j] = *(const short8*)(peb + j * 16 * KLORA + ks * 32);
        #pragma unroll
        for (int i = 0; i < 4; i++)
            #pragma unroll
            for (int j = 0; j < 4; j++)
                acc[i][j] = __builtin_amdgcn_mfma_f32_16x16x32_bf16(
                    ea[i], eb[j], acc[i][j], 0, 0, 0);
    }

    // store fp32
    #pragma unroll
    for (int i = 0; i < 4; i++) {
        #pragma unroll
        for (int j = 0; j < 4; j++) {
            int tt = m0 + wm * 64 + i * 16 + quad * 4;
            int jj = n0 + wn * 64 + j * 16 + col;
            float* po = out + (size_t)tt * DIM + jj;
            #pragma unroll
            for (int r = 0; r < 4; r++) po[(size_t)r * DIM] = acc[i][j][r];
        }
    }
}

// ------------------------------------------------------------------- launch
extern "C" void kernel_launch(void* const* d_in, const int* in_sizes, int n_in,
                              void* d_out, int out_size, void* d_ws, size_t ws_size,
                              hipStream_t stream)
{
    (void)in_sizes; (void)n_in; (void)out_size; (void)ws_size;
    const float* x      = (const float*)d_in[0];
    const float* gate_w = (const float*)d_in[1];
    const float* gate_b = (const float*)d_in[2];
    const float* base_w = (const float*)d_in[3];
    const float* base_b = (const float*)d_in[4];
    const float* lora_A = (const float*)d_in[5];
    const float* lora_B = (const float*)d_in[6];

    float* out   = (float*)d_out;                    // [8192, 2048]
    float* probs = out + (size_t)NTOK * DIM;         // [8192, 8]

    // workspace layout (~45.2 MB)
    char* ws = (char*)d_ws;
    bf16*  Xb   = (bf16*)ws;                          // 33,554,432 B
    bf16*  Wb   = (bf16*)(ws + 33554432);             //  8,388,608 B
    bf16*  A2   = (bf16*)(ws + 41943040);             //  2,097,152 B
    bf16*  Bt   = (bf16*)(ws + 44040192);             //    524,288 B
    bf16*  Ab   = (bf16*)(ws + 44564480);             //    524,288 B
    int*   idx  = (int*) (ws + 45088768);             //     32,768 B
    float* wsel = (float*)(ws + 45121536);            //     32,768 B

    cvt_logits_kernel<<<1024 + 2048 + 256 + 128, 256, 0, stream>>>(
        x, gate_w, gate_b, base_w, lora_B, lora_A,
        Xb, Wb, Bt, Ab, probs, idx, wsel);
    hsel_kernel<<<dim3(256, 2), 256, 0, stream>>>(Xb, Ab, idx, wsel, A2);
    gemm_kernel<<<dim3(64, 16), 256, 0, stream>>>(Xb, Wb, base_b, A2, Bt, out);
}